// Round 11
// baseline (229.623 us; speedup 1.0000x reference)
//
#include <hip/hip_runtime.h>

#define N_NODES 50000
#define N_EDGES 640000
#define D 128

#define SCAN_BLOCK 256
#define SCAN_NBLK ((N_NODES + SCAN_BLOCK - 1) / SCAN_BLOCK)  // 196

typedef __attribute__((ext_vector_type(8))) short bf16x8;   // 8 bf16 (4 VGPRs)
typedef __attribute__((ext_vector_type(4))) float f32x4;

__device__ __forceinline__ unsigned short f2bf(float f) {
    union { float f; unsigned u; } v; v.f = f;
    unsigned u = v.u;
    unsigned r = u + 0x7FFFu + ((u >> 16) & 1u);   // RNE
    return (unsigned short)(r >> 16);
}
__device__ __forceinline__ float bf2f(unsigned short s) {
    union { unsigned u; float f; } v; v.u = ((unsigned)s) << 16; return v.f;
}

// ---------------------------------------------------------------------------
// Degree histogram: deg[dst]++ per edge (int atomics, one-time)
// ---------------------------------------------------------------------------
__global__ void deg_kernel(const int* __restrict__ dst, int* __restrict__ deg) {
    int e = blockIdx.x * blockDim.x + threadIdx.x;
    if (e < N_EDGES) atomicAdd(&deg[dst[e]], 1);
}

// ---------------------------------------------------------------------------
// Scan step 1: per-block sums of deg (196 blocks x 256)
// ---------------------------------------------------------------------------
__global__ __launch_bounds__(SCAN_BLOCK) void scan_partial(const int* __restrict__ deg,
                                                           int* __restrict__ partial) {
    __shared__ int sm[SCAN_BLOCK];
    const int t = threadIdx.x;
    const int i = blockIdx.x * SCAN_BLOCK + t;
    sm[t] = (i < N_NODES) ? deg[i] : 0;
    __syncthreads();
#pragma unroll
    for (int off = SCAN_BLOCK / 2; off > 0; off >>= 1) {
        if (t < off) sm[t] += sm[t + off];
        __syncthreads();
    }
    if (t == 0) partial[blockIdx.x] = sm[0];
}

// ---------------------------------------------------------------------------
// Scan step 2 (merged): each block re-reduces partial[0..b) (L2-hot, 196 ints)
// for its own offset, then local exclusive scan -> row_off, cursor.
// ---------------------------------------------------------------------------
__global__ __launch_bounds__(SCAN_BLOCK) void scan_final2(const int* __restrict__ deg,
                                                          const int* __restrict__ partial,
                                                          int* __restrict__ row_off,
                                                          int* __restrict__ cursor) {
    __shared__ int sm[SCAN_BLOCK];
    const int t = threadIdx.x;
    const int b = blockIdx.x;

    // block offset = sum of partial[0..b)
    int acc = 0;
    for (int i = t; i < b; i += SCAN_BLOCK) acc += partial[i];
    sm[t] = acc;
    __syncthreads();
#pragma unroll
    for (int off = SCAN_BLOCK / 2; off > 0; off >>= 1) {
        if (t < off) sm[t] += sm[t + off];
        __syncthreads();
    }
    const int boff = sm[0];
    __syncthreads();

    // local Hillis-Steele inclusive scan
    const int i = b * SCAN_BLOCK + t;
    int v = (i < N_NODES) ? deg[i] : 0;
    sm[t] = v;
    __syncthreads();
    int x = v;
#pragma unroll
    for (int off = 1; off < SCAN_BLOCK; off <<= 1) {
        int y = (t >= off) ? sm[t - off] : 0;
        __syncthreads();
        x += y;
        sm[t] = x;
        __syncthreads();
    }
    int excl = x - v + boff;
    if (i < N_NODES) {
        row_off[i] = excl;
        cursor[i] = excl;
    }
    if (b == SCAN_NBLK - 1 && t == SCAN_BLOCK - 1) row_off[N_NODES] = x + boff;
}

// ---------------------------------------------------------------------------
// CSR fill: csr_src[cursor[dst[e]]++] = src[e]
// ---------------------------------------------------------------------------
__global__ void fill_csr(const int* __restrict__ src, const int* __restrict__ dst,
                         int* __restrict__ cursor, int* __restrict__ csr_src) {
    int e = blockIdx.x * blockDim.x + threadIdx.x;
    if (e < N_EDGES) {
        int pos = atomicAdd(&cursor[dst[e]], 1);
        csr_src[pos] = src[e];
    }
}

// ---------------------------------------------------------------------------
// Fused one-time conversions + deg zeroing:
// blocks [0,3125): x->bf16 ; [3125,3253): Wt1 ; [3253,3381): Wt2 ;
// [3381,3577): zero deg
// ---------------------------------------------------------------------------
__global__ void cvt_and_wt(const float* __restrict__ x,
                           const float* __restrict__ W1l, const float* __restrict__ W1r,
                           const float* __restrict__ W2l, const float* __restrict__ W2r,
                           unsigned short* __restrict__ x_bf,
                           unsigned short* __restrict__ Wt1,
                           unsigned short* __restrict__ Wt2,
                           int* __restrict__ deg) {
    const int b = blockIdx.x;
    const int t = threadIdx.x;
    if (b < 3125) {                     // 3125*256*8 = 6.4M = N_NODES*D exactly
        int i = b * 256 + t;
        float4 a = *reinterpret_cast<const float4*>(&x[(size_t)i * 8]);
        float4 c = *reinterpret_cast<const float4*>(&x[(size_t)i * 8 + 4]);
        bf16x8 o;
        o[0] = (short)f2bf(a.x); o[1] = (short)f2bf(a.y);
        o[2] = (short)f2bf(a.z); o[3] = (short)f2bf(a.w);
        o[4] = (short)f2bf(c.x); o[5] = (short)f2bf(c.y);
        o[6] = (short)f2bf(c.z); o[7] = (short)f2bf(c.w);
        *reinterpret_cast<bf16x8*>(&x_bf[(size_t)i * 8]) = o;
    } else if (b < 3381) {
        const bool second = (b >= 3125 + 128);
        const float* Wl = second ? W2l : W1l;
        const float* Wr = second ? W2r : W1r;
        unsigned short* Wt = second ? Wt2 : Wt1;
        int i = (b - (second ? 3253 : 3125)) * 256 + t;   // 0..32767
        int c = i >> 8, k = i & 255;
        float v = (k < 128) ? Wl[k * 128 + c] : Wr[(k - 128) * 128 + c];
        Wt[c * 256 + k] = f2bf(v);
    } else {
        int i = (b - 3381) * 256 + t;
        if (i < N_NODES) deg[i] = 0;
    }
}

// ---------------------------------------------------------------------------
// Fused gather + MFMA GEMM, 2-phase LDS (32KB -> 4 blocks/CU, 32 waves/CU):
//   out = [relu]( [mean(Aroot)|Aroot] @ [Wl;Wr] + bias )
// 512 thr / 8 waves, BM=128 rows (16/wave). Wt staged in LDS 64 cols at a
// time (XOR-swizzled 16B entries); MFMA runs in two col-phases with a[8]
// frags held in registers. Gather produces mean A-frags directly in MFMA
// layout: lane l owns row l&15, k-cols (l>>4)*8+[0,8) per 32-chunk; 4
// lanes/node walk the CSR list (2-way unrolled, fp32 accumulate, one bf16
// round at the end).
// ---------------------------------------------------------------------------
template <bool RELU, bool OUTBF16>
__global__ __launch_bounds__(512, 8) void sage_fused(
    const unsigned short* __restrict__ Aroot,   // [N,128] bf16 (x or h)
    const int* __restrict__ row_off,
    const int* __restrict__ csr_src,
    const unsigned short* __restrict__ Wt,      // [128 cols][256 k] bf16
    const float* __restrict__ bias,             // [128] fp32
    float* __restrict__ outf,                   // fp32 out (if !OUTBF16)
    unsigned short* __restrict__ outb)          // bf16 out (if OUTBF16)
{
    __shared__ bf16x8 ws[2048];                 // 32KB: swizzled half of Wt
    const int t = threadIdx.x;
    const int w = t >> 6;
    const int l = t & 63;
    const int row0 = blockIdx.x * 128 + w * 16;

    int node = row0 + (l & 15);
    if (node >= N_NODES) node = N_NODES - 1;    // clamp; C-write guarded
    const int k8 = (l >> 4) * 8;

    // stage phase 0: cols [0,64)  (stores issued before the gather)
#pragma unroll
    for (int i = 0; i < 4; ++i) {
        int s = i * 512 + t;                    // 0..2047
        int col = s >> 5;
        int chunk = s & 31;
        ws[col * 32 + (chunk ^ (col & 7))] =
            *reinterpret_cast<const bf16x8*>(&Wt[((size_t)col * 32 + chunk) * 8]);
    }

    // gather mean fragments in-register (frag layout)
    const int beg = row_off[node];
    const int end = row_off[node + 1];
    float s[4][8] = {};
    int k = beg;
    for (; k + 1 < end; k += 2) {
        int n0 = csr_src[k];
        int n1 = csr_src[k + 1];
        const unsigned short* b0 = &Aroot[(size_t)n0 * D + k8];
        const unsigned short* b1 = &Aroot[(size_t)n1 * D + k8];
        bf16x8 v0[4], v1[4];
#pragma unroll
        for (int kc = 0; kc < 4; ++kc)
            v0[kc] = *reinterpret_cast<const bf16x8*>(b0 + kc * 32);
#pragma unroll
        for (int kc = 0; kc < 4; ++kc)
            v1[kc] = *reinterpret_cast<const bf16x8*>(b1 + kc * 32);
#pragma unroll
        for (int kc = 0; kc < 4; ++kc)
#pragma unroll
            for (int j = 0; j < 8; ++j)
                s[kc][j] += bf2f((unsigned short)v0[kc][j])
                          + bf2f((unsigned short)v1[kc][j]);
    }
    if (k < end) {
        int n0 = csr_src[k];
        const unsigned short* b0 = &Aroot[(size_t)n0 * D + k8];
#pragma unroll
        for (int kc = 0; kc < 4; ++kc) {
            bf16x8 v0 = *reinterpret_cast<const bf16x8*>(b0 + kc * 32);
#pragma unroll
            for (int j = 0; j < 8; ++j) s[kc][j] += bf2f((unsigned short)v0[j]);
        }
    }

    bf16x8 a[8];
    {
        const float inv = 1.0f / fmaxf((float)(end - beg), 1.0f);
#pragma unroll
        for (int kc = 0; kc < 4; ++kc) {
            bf16x8 o;
#pragma unroll
            for (int j = 0; j < 8; ++j) o[j] = (short)f2bf(s[kc][j] * inv);
            a[kc] = o;
        }
    }
#pragma unroll
    for (int kc = 0; kc < 4; ++kc)
        a[4 + kc] = *reinterpret_cast<const bf16x8*>(
            &Aroot[(size_t)node * D + kc * 32 + k8]);

    __syncthreads();

    f32x4 acc[8] = {};
    const int l15 = l & 15;
    const int kg = l >> 4;
    const int swz = l & 7;

    // phase 0: cols 0..63 (c = 0..3)
#pragma unroll
    for (int kc = 0; kc < 8; ++kc) {
#pragma unroll
        for (int c = 0; c < 4; ++c) {
            bf16x8 bfr = ws[c * 512 + l15 * 32 + ((kc * 4 + kg) ^ swz)];
            acc[c] = __builtin_amdgcn_mfma_f32_16x16x32_bf16(a[kc], bfr, acc[c], 0, 0, 0);
        }
    }
    __syncthreads();

    // stage phase 1: cols [64,128)
#pragma unroll
    for (int i = 0; i < 4; ++i) {
        int s2 = i * 512 + t;
        int col = s2 >> 5;
        int chunk = s2 & 31;
        ws[col * 32 + (chunk ^ (col & 7))] =
            *reinterpret_cast<const bf16x8*>(&Wt[((size_t)(64 + col) * 32 + chunk) * 8]);
    }
    __syncthreads();

    // phase 1: cols 64..127 (c = 4..7)
#pragma unroll
    for (int kc = 0; kc < 8; ++kc) {
#pragma unroll
        for (int c = 4; c < 8; ++c) {
            bf16x8 bfr = ws[(c - 4) * 512 + l15 * 32 + ((kc * 4 + kg) ^ swz)];
            acc[c] = __builtin_amdgcn_mfma_f32_16x16x32_bf16(a[kc], bfr, acc[c], 0, 0, 0);
        }
    }

    const int rbase = row0 + kg * 4;
#pragma unroll
    for (int c = 0; c < 8; ++c) {
        const int col = c * 16 + l15;
        const float b = bias[col];
#pragma unroll
        for (int i = 0; i < 4; ++i) {
            int r = rbase + i;
            if (r < N_NODES) {
                float v = acc[c][i] + b;
                if (RELU) v = fmaxf(v, 0.f);
                if (OUTBF16) outb[(size_t)r * D + col] = f2bf(v);
                else         outf[(size_t)r * D + col] = v;
            }
        }
    }
}

// ---------------------------------------------------------------------------
extern "C" void kernel_launch(void* const* d_in, const int* in_sizes, int n_in,
                              void* d_out, int out_size, void* d_ws, size_t ws_size,
                              hipStream_t stream) {
    const float* x   = (const float*)d_in[0];
    const int*   ei  = (const int*)d_in[1];
    const float* W1l = (const float*)d_in[2];
    const float* b1  = (const float*)d_in[3];
    const float* W1r = (const float*)d_in[4];
    const float* W2l = (const float*)d_in[5];
    const float* b2  = (const float*)d_in[6];
    const float* W2r = (const float*)d_in[7];
    float* out = (float*)d_out;

    const int* src = ei;             // edge_index[0]
    const int* dst = ei + N_EDGES;   // edge_index[1]

    // Workspace layout (ints first, then bf16 arrays; all 16B aligned)
    int* deg       = (int*)d_ws;                     // 51200
    int* row_off   = deg + 51200;                    // 51200 (N+1 used)
    int* cursor    = row_off + 51200;                // 51200
    int* partial   = cursor + 51200;                 // 256
    int* block_off = partial + 256;                  // 256 (unused now)
    int* csr_src   = block_off + 256;                // 640000
    unsigned short* x_bf = (unsigned short*)(csr_src + N_EDGES);     // N*D
    unsigned short* h_bf = x_bf + (size_t)N_NODES * D;               // N*D
    unsigned short* Wt1  = h_bf + (size_t)N_NODES * D;               // 128*256
    unsigned short* Wt2  = Wt1 + 128 * 256;                          // 128*256

    // ---- one-time: conversions + deg zero (1 kernel), then CSR build ----
    cvt_and_wt<<<3577, 256, 0, stream>>>(x, W1l, W1r, W2l, W2r, x_bf, Wt1, Wt2, deg);
    deg_kernel<<<(N_EDGES + 255) / 256, 256, 0, stream>>>(dst, deg);
    scan_partial<<<SCAN_NBLK, SCAN_BLOCK, 0, stream>>>(deg, partial);
    scan_final2<<<SCAN_NBLK, SCAN_BLOCK, 0, stream>>>(deg, partial, row_off, cursor);
    fill_csr<<<(N_EDGES + 255) / 256, 256, 0, stream>>>(src, dst, cursor, csr_src);

    const int gemm_grid = (N_NODES + 127) / 128;      // 391

    // ---- layer 1 (gather fused into GEMM) ----
    sage_fused<true, true><<<gemm_grid, 512, 0, stream>>>(
        x_bf, row_off, csr_src, Wt1, b1, nullptr, h_bf);

    // ---- layer 2 ----
    sage_fused<false, false><<<gemm_grid, 512, 0, stream>>>(
        h_bf, row_off, csr_src, Wt2, b2, out, nullptr);
}

// Round 12
// 153.440 us; speedup vs baseline: 1.4965x; 1.4965x over previous
//
#include <hip/hip_runtime.h>

#define N_NODES 50000
#define N_EDGES 640000
#define D 128

#define SCAN_BLOCK 256
#define SCAN_NBLK ((N_NODES + SCAN_BLOCK - 1) / SCAN_BLOCK)  // 196

typedef __attribute__((ext_vector_type(8))) short bf16x8;   // 8 bf16 (4 VGPRs)
typedef __attribute__((ext_vector_type(4))) float f32x4;

__device__ __forceinline__ unsigned short f2bf(float f) {
    union { float f; unsigned u; } v; v.f = f;
    unsigned u = v.u;
    unsigned r = u + 0x7FFFu + ((u >> 16) & 1u);   // RNE
    return (unsigned short)(r >> 16);
}
__device__ __forceinline__ float bf2f(unsigned short s) {
    union { unsigned u; float f; } v; v.u = ((unsigned)s) << 16; return v.f;
}

// ---------------------------------------------------------------------------
// Degree histogram: deg[dst]++ per edge (int atomics, one-time)
// ---------------------------------------------------------------------------
__global__ void deg_kernel(const int* __restrict__ dst, int* __restrict__ deg) {
    int e = blockIdx.x * blockDim.x + threadIdx.x;
    if (e < N_EDGES) atomicAdd(&deg[dst[e]], 1);
}

// ---------------------------------------------------------------------------
// Scan step 1: per-block sums of deg (196 blocks x 256)
// ---------------------------------------------------------------------------
__global__ __launch_bounds__(SCAN_BLOCK) void scan_partial(const int* __restrict__ deg,
                                                           int* __restrict__ partial) {
    __shared__ int sm[SCAN_BLOCK];
    const int t = threadIdx.x;
    const int i = blockIdx.x * SCAN_BLOCK + t;
    sm[t] = (i < N_NODES) ? deg[i] : 0;
    __syncthreads();
#pragma unroll
    for (int off = SCAN_BLOCK / 2; off > 0; off >>= 1) {
        if (t < off) sm[t] += sm[t + off];
        __syncthreads();
    }
    if (t == 0) partial[blockIdx.x] = sm[0];
}

// ---------------------------------------------------------------------------
// Scan step 2 (merged): block offset from partial[0..b) (L2-hot), then local
// exclusive scan -> row_off, cursor.
// ---------------------------------------------------------------------------
__global__ __launch_bounds__(SCAN_BLOCK) void scan_final2(const int* __restrict__ deg,
                                                          const int* __restrict__ partial,
                                                          int* __restrict__ row_off,
                                                          int* __restrict__ cursor) {
    __shared__ int sm[SCAN_BLOCK];
    const int t = threadIdx.x;
    const int b = blockIdx.x;

    int acc = 0;
    for (int i = t; i < b; i += SCAN_BLOCK) acc += partial[i];
    sm[t] = acc;
    __syncthreads();
#pragma unroll
    for (int off = SCAN_BLOCK / 2; off > 0; off >>= 1) {
        if (t < off) sm[t] += sm[t + off];
        __syncthreads();
    }
    const int boff = sm[0];
    __syncthreads();

    const int i = b * SCAN_BLOCK + t;
    int v = (i < N_NODES) ? deg[i] : 0;
    sm[t] = v;
    __syncthreads();
    int x = v;
#pragma unroll
    for (int off = 1; off < SCAN_BLOCK; off <<= 1) {
        int y = (t >= off) ? sm[t - off] : 0;
        __syncthreads();
        x += y;
        sm[t] = x;
        __syncthreads();
    }
    int excl = x - v + boff;
    if (i < N_NODES) {
        row_off[i] = excl;
        cursor[i] = excl;
    }
    if (b == SCAN_NBLK - 1 && t == SCAN_BLOCK - 1) row_off[N_NODES] = x + boff;
}

// ---------------------------------------------------------------------------
// CSR fill: csr_src[cursor[dst[e]]++] = src[e]
// ---------------------------------------------------------------------------
__global__ void fill_csr(const int* __restrict__ src, const int* __restrict__ dst,
                         int* __restrict__ cursor, int* __restrict__ csr_src) {
    int e = blockIdx.x * blockDim.x + threadIdx.x;
    if (e < N_EDGES) {
        int pos = atomicAdd(&cursor[dst[e]], 1);
        csr_src[pos] = src[e];
    }
}

// ---------------------------------------------------------------------------
// Fused one-time conversions + deg zeroing:
// blocks [0,3125): x->bf16 ; [3125,3253): Wt1 ; [3253,3381): Wt2 ;
// [3381,3577): zero deg
// ---------------------------------------------------------------------------
__global__ void cvt_and_wt(const float* __restrict__ x,
                           const float* __restrict__ W1l, const float* __restrict__ W1r,
                           const float* __restrict__ W2l, const float* __restrict__ W2r,
                           unsigned short* __restrict__ x_bf,
                           unsigned short* __restrict__ Wt1,
                           unsigned short* __restrict__ Wt2,
                           int* __restrict__ deg) {
    const int b = blockIdx.x;
    const int t = threadIdx.x;
    if (b < 3125) {                     // 3125*256*8 = 6.4M = N_NODES*D exactly
        int i = b * 256 + t;
        float4 a = *reinterpret_cast<const float4*>(&x[(size_t)i * 8]);
        float4 c = *reinterpret_cast<const float4*>(&x[(size_t)i * 8 + 4]);
        bf16x8 o;
        o[0] = (short)f2bf(a.x); o[1] = (short)f2bf(a.y);
        o[2] = (short)f2bf(a.z); o[3] = (short)f2bf(a.w);
        o[4] = (short)f2bf(c.x); o[5] = (short)f2bf(c.y);
        o[6] = (short)f2bf(c.z); o[7] = (short)f2bf(c.w);
        *reinterpret_cast<bf16x8*>(&x_bf[(size_t)i * 8]) = o;
    } else if (b < 3381) {
        const bool second = (b >= 3125 + 128);
        const float* Wl = second ? W2l : W1l;
        const float* Wr = second ? W2r : W1r;
        unsigned short* Wt = second ? Wt2 : Wt1;
        int i = (b - (second ? 3253 : 3125)) * 256 + t;   // 0..32767
        int c = i >> 8, k = i & 255;
        float v = (k < 128) ? Wl[k * 128 + c] : Wr[(k - 128) * 128 + c];
        Wt[c * 256 + k] = f2bf(v);
    } else {
        int i = (b - 3381) * 256 + t;
        if (i < N_NODES) deg[i] = 0;
    }
}

// ---------------------------------------------------------------------------
// Gather-aggregate (bf16 in/out, fp32 accumulate): one wave per node.
// Group g (16 lanes) handles neighbors beg+g*4+{0..3}, stride 16: per trip
// 4 row loads in flight per lane (16 rows/wave); next trip's csr indices
// prefetched before the accumulate to break the idx->row dependency chain.
// ---------------------------------------------------------------------------
__global__ __launch_bounds__(256) void gather_bf16(const unsigned short* __restrict__ feat,
                                                   const int* __restrict__ row_off,
                                                   const int* __restrict__ csr_src,
                                                   unsigned short* __restrict__ mean) {
    int node = (blockIdx.x * 256 + threadIdx.x) >> 6;   // wave-uniform
    int l = threadIdx.x & 63;
    int grp = l >> 4;
    int c8 = (l & 15) * 8;
    int beg = row_off[node];
    int end = row_off[node + 1];

    float s[8] = {};
    int kb = beg + grp * 4;
    int idx[4];
#pragma unroll
    for (int j = 0; j < 4; ++j) {
        int k = kb + j;
        idx[j] = (kb < end) ? csr_src[k < end ? k : end - 1] : 0;
    }
    while (kb < end) {
        bf16x8 v[4];
#pragma unroll
        for (int j = 0; j < 4; ++j)
            v[j] = *reinterpret_cast<const bf16x8*>(&feat[(size_t)idx[j] * D + c8]);
        int kb_n = kb + 16;
        int idx_n[4];
#pragma unroll
        for (int j = 0; j < 4; ++j) {             // prefetch next trip's indices
            int k = kb_n + j;
            idx_n[j] = (kb_n < end) ? csr_src[k < end ? k : end - 1] : 0;
        }
#pragma unroll
        for (int j = 0; j < 4; ++j) {
            float m = (kb + j < end) ? 1.0f : 0.0f;
#pragma unroll
            for (int q = 0; q < 8; ++q) s[q] += m * bf2f((unsigned short)v[j][q]);
        }
        kb = kb_n;
#pragma unroll
        for (int j = 0; j < 4; ++j) idx[j] = idx_n[j];
    }
#pragma unroll
    for (int j = 0; j < 8; ++j) {
        float v = s[j];
        v += __shfl_xor(v, 16, 64);
        v += __shfl_xor(v, 32, 64);
        s[j] = v;
    }
    if (grp == 0) {
        float inv = 1.0f / fmaxf((float)(end - beg), 1.0f);
        bf16x8 o;
#pragma unroll
        for (int j = 0; j < 8; ++j) o[j] = (short)f2bf(s[j] * inv);
        *reinterpret_cast<bf16x8*>(&mean[(size_t)node * D + c8]) = o;
    }
}

// ---------------------------------------------------------------------------
// MFMA GEMM with LDS-staged W: out = [relu]( [mean|root] @ [Wl;Wr] + bias ).
// 512 thr / 8 waves, BM=128 rows (16/wave). Whole Wt (64KB) in LDS, XOR-
// swizzled 16B entries (conflict-free stage + frag reads). A-frags hoisted.
// ---------------------------------------------------------------------------
template <bool RELU, bool OUTBF16>
__global__ __launch_bounds__(512) void sage_gemm_mfma(
    const unsigned short* __restrict__ Amean,   // [N,128] bf16
    const unsigned short* __restrict__ Aroot,   // [N,128] bf16
    const unsigned short* __restrict__ Wt,      // [128 cols][256 k] bf16
    const float* __restrict__ bias,             // [128] fp32
    float* __restrict__ outf,                   // fp32 out (if !OUTBF16)
    unsigned short* __restrict__ outb)          // bf16 out (if OUTBF16)
{
    __shared__ bf16x8 ws[4096];                 // 64KB: swizzled Wt
    const int t = threadIdx.x;
    const int w = t >> 6;
    const int l = t & 63;
    const int row0 = blockIdx.x * 128 + w * 16;

    int arow = row0 + (l & 15);
    if (arow >= N_NODES) arow = N_NODES - 1;    // clamp; C-write guarded
    const int k8 = (l >> 4) * 8;

    bf16x8 a[8];
#pragma unroll
    for (int kc = 0; kc < 8; ++kc) {
        const unsigned short* ap = (kc < 4)
            ? &Amean[(size_t)arow * D + kc * 32 + k8]
            : &Aroot[(size_t)arow * D + (kc - 4) * 32 + k8];
        a[kc] = *reinterpret_cast<const bf16x8*>(ap);
    }

#pragma unroll
    for (int i = 0; i < 8; ++i) {
        int g = i * 512 + t;                    // 16B chunk index in Wt
        int col = g >> 5;
        int chunk = g & 31;
        ws[col * 32 + (chunk ^ (col & 7))] =
            *reinterpret_cast<const bf16x8*>(&Wt[(size_t)g * 8]);
    }
    __syncthreads();

    f32x4 acc[8] = {};
    const int l15 = l & 15;
    const int kg = l >> 4;
    const int swz = l & 7;
#pragma unroll
    for (int kc = 0; kc < 8; ++kc) {
#pragma unroll
        for (int c = 0; c < 8; ++c) {
            bf16x8 bfr = ws[c * 512 + l15 * 32 + ((kc * 4 + kg) ^ swz)];
            acc[c] = __builtin_amdgcn_mfma_f32_16x16x32_bf16(a[kc], bfr, acc[c], 0, 0, 0);
        }
    }

    const int rbase = row0 + kg * 4;
#pragma unroll
    for (int c = 0; c < 8; ++c) {
        const int col = c * 16 + l15;
        const float b = bias[col];
#pragma unroll
        for (int i = 0; i < 4; ++i) {
            int r = rbase + i;
            if (r < N_NODES) {
                float v = acc[c][i] + b;
                if (RELU) v = fmaxf(v, 0.f);
                if (OUTBF16) outb[(size_t)r * D + col] = f2bf(v);
                else         outf[(size_t)r * D + col] = v;
            }
        }
    }
}

// ---------------------------------------------------------------------------
extern "C" void kernel_launch(void* const* d_in, const int* in_sizes, int n_in,
                              void* d_out, int out_size, void* d_ws, size_t ws_size,
                              hipStream_t stream) {
    const float* x   = (const float*)d_in[0];
    const int*   ei  = (const int*)d_in[1];
    const float* W1l = (const float*)d_in[2];
    const float* b1  = (const float*)d_in[3];
    const float* W1r = (const float*)d_in[4];
    const float* W2l = (const float*)d_in[5];
    const float* b2  = (const float*)d_in[6];
    const float* W2r = (const float*)d_in[7];
    float* out = (float*)d_out;

    const int* src = ei;             // edge_index[0]
    const int* dst = ei + N_EDGES;   // edge_index[1]

    // Workspace layout (ints first, then bf16 arrays; all 16B aligned)
    int* deg       = (int*)d_ws;                     // 51200
    int* row_off   = deg + 51200;                    // 51200 (N+1 used)
    int* cursor    = row_off + 51200;                // 51200
    int* partial   = cursor + 51200;                 // 256
    int* pad       = partial + 256;                  // 256
    int* csr_src   = pad + 256;                      // 640000
    unsigned short* x_bf    = (unsigned short*)(csr_src + N_EDGES);  // N*D
    unsigned short* h_bf    = x_bf + (size_t)N_NODES * D;            // N*D
    unsigned short* mean_bf = h_bf + (size_t)N_NODES * D;            // N*D
    unsigned short* Wt1     = mean_bf + (size_t)N_NODES * D;         // 128*256
    unsigned short* Wt2     = Wt1 + 128 * 256;                       // 128*256

    // ---- one-time: conversions + deg zero (1 kernel), then CSR build ----
    cvt_and_wt<<<3577, 256, 0, stream>>>(x, W1l, W1r, W2l, W2r, x_bf, Wt1, Wt2, deg);
    deg_kernel<<<(N_EDGES + 255) / 256, 256, 0, stream>>>(dst, deg);
    scan_partial<<<SCAN_NBLK, SCAN_BLOCK, 0, stream>>>(deg, partial);
    scan_final2<<<SCAN_NBLK, SCAN_BLOCK, 0, stream>>>(deg, partial, row_off, cursor);
    fill_csr<<<(N_EDGES + 255) / 256, 256, 0, stream>>>(src, dst, cursor, csr_src);

    const int gather_grid = N_NODES * 64 / 256;       // 12500
    const int gemm_grid = (N_NODES + 127) / 128;      // 391

    // ---- layer 1 ----
    gather_bf16<<<gather_grid, 256, 0, stream>>>(x_bf, row_off, csr_src, mean_bf);
    sage_gemm_mfma<true, true><<<gemm_grid, 512, 0, stream>>>(
        mean_bf, x_bf, Wt1, b1, nullptr, h_bf);

    // ---- layer 2 ----
    gather_bf16<<<gather_grid, 256, 0, stream>>>(h_bf, row_off, csr_src, mean_bf);
    sage_gemm_mfma<false, false><<<gemm_grid, 512, 0, stream>>>(
        mean_bf, h_bf, Wt2, b2, out, nullptr);
}